// Round 1
// 1323.013 us; speedup vs baseline: 2.6295x; 2.6295x over previous
//
#include <hip/hip_runtime.h>
#include <math.h>

// ---------------- problem constants ----------------
constexpr int Nn = 50000;
constexpr int Ee = 800000;
// output layout (f32 elements): [out_s N*64 | vec N*3 | node_feats_out N*256]
constexpr int VEC_OFF = Nn * 64;            // 3,200,000
constexpr int NF_OFF  = Nn * 67;            // 3,350,000

// ---------------- ws layout (bytes) — total exactly 51.2 MB ----------------
constexpr size_t AS_OFF = 0;                // f32 N*64   12.8 MB (atomic accum)
constexpr size_t AV_OFF = 12800000;         // f32 N*192  38.4 MB (atomic accum)

__device__ __forceinline__ float silu(float x) { return x / (1.f + __expf(-x)); }

// ================= K0: per-node up-projection =================
// up[n] (256 f32) = [ s@Wsu (64) | (v@Wvu) transposed as [i][k] (3*64) ]
// Scratch target: node_feats_out region of the output buffer (overwritten
// later by k_post). Removes the 16x-redundant per-edge GEMV from k_edge.
__global__ __launch_bounds__(256) void k_up(
    const float* __restrict__ nfeat,
    const float* __restrict__ Wsu, const float* __restrict__ Wvu,
    float* __restrict__ up) {
    __shared__ float sS[4][8][64];        // s part per wave/node
    __shared__ float sT[4][8][3][64];     // v part transposed [i][c]

    const int tid = threadIdx.x, lane = tid & 63, w = tid >> 6;
    const int nb = blockIdx.x * 32 + w * 8;

    // stage 8 node rows (coalesced float4, scatter split s/v)
#pragma unroll
    for (int nn = 0; nn < 8; nn++) {
        int n = nb + nn;
        if (n < Nn) {
            const float4 nv = *(const float4*)(nfeat + (size_t)n * 256 + lane * 4);
#pragma unroll
            for (int j = 0; j < 4; j++) {
                float val = (j == 0) ? nv.x : ((j == 1) ? nv.y : ((j == 2) ? nv.z : nv.w));
                int cc = lane * 4 + j;
                if (cc < 64) {
                    sS[w][nn][cc] = val;
                } else {
                    int t = cc - 64;               // v[c][i] = nf[64 + 3c + i]
                    sT[w][nn][t - (t / 3) * 3][t / 3] = val;
                }
            }
        }
    }
    // same-wave LDS write->read: in-order, no barrier needed

#pragma unroll
    for (int nn = 0; nn < 8; nn++) {
        int n = nb + nn;
        if (n >= Nn) continue;
        float su = 0.f, v0 = 0.f, v1 = 0.f, v2 = 0.f;
        for (int c = 0; c < 64; c += 4) {
            const float4 sv = *(const float4*)(&sS[w][nn][c]);
            const float4 t0 = *(const float4*)(&sT[w][nn][0][c]);
            const float4 t1 = *(const float4*)(&sT[w][nn][1][c]);
            const float4 t2 = *(const float4*)(&sT[w][nn][2][c]);
            float u0 = Wsu[(c + 0) * 64 + lane], u1 = Wsu[(c + 1) * 64 + lane],
                  u2 = Wsu[(c + 2) * 64 + lane], u3 = Wsu[(c + 3) * 64 + lane];
            float q0 = Wvu[(c + 0) * 64 + lane], q1 = Wvu[(c + 1) * 64 + lane],
                  q2 = Wvu[(c + 2) * 64 + lane], q3 = Wvu[(c + 3) * 64 + lane];
            su += sv.x * u0 + sv.y * u1 + sv.z * u2 + sv.w * u3;
            v0 += t0.x * q0 + t0.y * q1 + t0.z * q2 + t0.w * q3;
            v1 += t1.x * q0 + t1.y * q1 + t1.z * q2 + t1.w * q3;
            v2 += t2.x * q0 + t2.y * q1 + t2.z * q2 + t2.w * q3;
        }
        float* o = up + (size_t)n * 256;
        o[lane]       = su;
        o[64 + lane]  = v0;
        o[128 + lane] = v1;
        o[192 + lane] = v2;
    }
}

// ================= K1: fused edge kernel (pure f32 VALU) =================
// Per block: 32 edges. Per wave: 8 edges.
//  1. h = silu(ef @ W1)          (lane = h channel)
//  2. w = h @ W2  (5 x 64 cols)  (lane = channel, acc wacc[5][8])
//  3. gather pre-projected (sj, vj) rows — 4 coalesced dword loads/edge,
//     ALL 32 loads issued before any compute (no LDS round-trip),
//     message compute, 4 atomicAdds.
__global__ __launch_bounds__(256, 3) void k_edge(
    const float* __restrict__ vectors, const float* __restrict__ edge_feats,
    const int* __restrict__ snd_idx, const int* __restrict__ rcv_idx,
    const float* __restrict__ up,
    const float* __restrict__ W1, const float* __restrict__ W2,
    float* __restrict__ a_s, float* __restrict__ a_v) {
    __shared__ float sEf[32 * 64];
    __shared__ float sH[32 * 64];
    __shared__ float sY[32 * 3];
    __shared__ int sSnd[32], sRcv[32];

    const int tid = threadIdx.x;
    const int e0 = blockIdx.x * 32;

    {   // stage edge_feats tile f32 (coalesced, 8 floats/thread)
        int row = tid >> 3, c0 = (tid & 7) * 8;
        const float4* src = (const float4*)(edge_feats + (size_t)(e0 + row) * 64 + c0);
        float4* dst = (float4*)(&sEf[row * 64 + c0]);
        dst[0] = src[0]; dst[1] = src[1];
    }
    if (tid < 32) {   // per-edge Y1 = sqrt(3)*rhat + indices
        int e = e0 + tid;
        float x = vectors[(size_t)e * 3 + 0];
        float y = vectors[(size_t)e * 3 + 1];
        float z = vectors[(size_t)e * 3 + 2];
        float n = sqrtf(x * x + y * y + z * z) + 1e-12f;
        float s = 1.7320508075688772f / n;
        sY[tid * 3 + 0] = x * s; sY[tid * 3 + 1] = y * s; sY[tid * 3 + 2] = z * s;
        sSnd[tid] = snd_idx[e];
        sRcv[tid] = rcv_idx[e];
    }
    __syncthreads();

    const int lane = tid & 63, w = tid >> 6, m0 = w * 8;

    // ---- h = silu(ef @ W1) ----
    {
        float hacc[8];
#pragma unroll
        for (int e = 0; e < 8; e++) hacc[e] = 0.f;
        for (int c = 0; c < 64; c += 4) {
            float w0 = W1[(c + 0) * 64 + lane], w1 = W1[(c + 1) * 64 + lane],
                  w2 = W1[(c + 2) * 64 + lane], w3 = W1[(c + 3) * 64 + lane];
#pragma unroll
            for (int e = 0; e < 8; e++) {
                const float4 ef = *(const float4*)(&sEf[(m0 + e) * 64 + c]);
                hacc[e] += ef.x * w0 + ef.y * w1 + ef.z * w2 + ef.w * w3;
            }
        }
#pragma unroll
        for (int e = 0; e < 8; e++) sH[(m0 + e) * 64 + lane] = silu(hacc[e]);
        // sH rows are wave-private: same-wave write->read, no barrier needed
    }

    // ---- w = h @ W2 : wacc[q][e] = w[e][q*64 + lane] ----
    float wacc[5][8];
#pragma unroll
    for (int q = 0; q < 5; q++)
#pragma unroll
        for (int e = 0; e < 8; e++) wacc[q][e] = 0.f;
#pragma unroll 2
    for (int c = 0; c < 64; c++) {
        float wq0 = W2[c * 320 + 0 * 64 + lane];
        float wq1 = W2[c * 320 + 1 * 64 + lane];
        float wq2 = W2[c * 320 + 2 * 64 + lane];
        float wq3 = W2[c * 320 + 3 * 64 + lane];
        float wq4 = W2[c * 320 + 4 * 64 + lane];
#pragma unroll
        for (int e = 0; e < 8; e++) {
            float hb = sH[(m0 + e) * 64 + c];
            wacc[0][e] += hb * wq0; wacc[1][e] += hb * wq1; wacc[2][e] += hb * wq2;
            wacc[3][e] += hb * wq3; wacc[4][e] += hb * wq4;
        }
    }

    // ---- gather pre-projected rows: issue ALL loads first (ILP) ----
    float sjv[8], v0v[8], v1v[8], v2v[8];
#pragma unroll
    for (int e = 0; e < 8; e++) {
        const float* row = up + (size_t)sSnd[m0 + e] * 256;
        sjv[e] = row[lane];
        v0v[e] = row[64 + lane];
        v1v[e] = row[128 + lane];
        v2v[e] = row[192 + lane];
    }

    // ---- message compute + scatter ----
#pragma unroll
    for (int e = 0; e < 8; e++) {
        const int rcv = sRcv[m0 + e];
        const float Y0 = sY[(m0 + e) * 3 + 0];
        const float Y1 = sY[(m0 + e) * 3 + 1];
        const float Y2 = sY[(m0 + e) * 3 + 2];
        const float sj = sjv[e], vj0 = v0v[e], vj1 = v1v[e], vj2 = v2v[e];
        const float w0 = wacc[0][e], w1 = wacc[1][e], w2 = wacc[2][e],
                    w3 = wacc[3][e], w4 = wacc[4][e];
        float vdY = vj0 * Y0 + vj1 * Y1 + vj2 * Y2;
        float ms = w0 * sj + w1 * vdY;
        float cx = vj1 * Y2 - vj2 * Y1;
        float cy = vj2 * Y0 - vj0 * Y2;
        float cz = vj0 * Y1 - vj1 * Y0;
        float t = w2 * sj;
        atomicAdd(a_s + (size_t)rcv * 64 + lane, ms);
        float* avp = a_v + (size_t)rcv * 192;
        atomicAdd(avp + lane,       t * Y0 + w3 * vj0 + w4 * cx);
        atomicAdd(avp + 64 + lane,  t * Y1 + w3 * vj1 + w4 * cy);
        atomicAdd(avp + 128 + lane, t * Y2 + w3 * vj2 + w4 * cz);
    }
}

// ================= K2: node post (pure f32 VALU) =================
// Block 256 = 4 waves; each wave owns 8 nodes. All weights read from
// global (L1/L2-hot, coalesced: lane = output channel). Per-wave LDS
// X/Y buffers; wave-private -> no barriers needed after staging.
__global__ __launch_bounds__(256) void k_post(
    const float* __restrict__ a_s, const float* __restrict__ a_v,
    const float* __restrict__ Wsp, const float* __restrict__ Wvp,
    const float* __restrict__ Ps1, const float* __restrict__ Ps2,
    const float* __restrict__ Ps3, const float* __restrict__ Pvv,
    const float* __restrict__ Pv1, const float* __restrict__ Pv2,
    const float* __restrict__ Pv3,
    const float* __restrict__ Rw1, const float* __restrict__ Rw2,
    const float* __restrict__ Rgate, const float* __restrict__ Rvmix,
    float* __restrict__ out) {
    __shared__ float Xb[4][8 * 256];   // a/16 -> (as2|av2) -> hr in s-section
    __shared__ float Yb[4][8 * 256];   // ps|pv0|pv1|pv2

    const int tid = threadIdx.x, lane = tid & 63, w = tid >> 6;
    const int nb = blockIdx.x * 32 + w * 8;   // first node of this wave
    float* X = &Xb[w][0];
    float* Y = &Yb[w][0];

    // ---- stage a_s/a_v (x 1/16) ----
#pragma unroll
    for (int nn = 0; nn < 8; nn++) {
        int n = nb + nn;
        if (n < Nn) {
            X[nn * 256 + lane]       = a_s[(size_t)n * 64 + lane] * 0.0625f;
            X[nn * 256 + 64 + lane]  = a_v[(size_t)n * 192 + lane] * 0.0625f;
            X[nn * 256 + 128 + lane] = a_v[(size_t)n * 192 + 64 + lane] * 0.0625f;
            X[nn * 256 + 192 + lane] = a_v[(size_t)n * 192 + 128 + lane] * 0.0625f;
        } else {
            X[nn * 256 + lane] = 0.f; X[nn * 256 + 64 + lane] = 0.f;
            X[nn * 256 + 128 + lane] = 0.f; X[nn * 256 + 192 + lane] = 0.f;
        }
    }

    // ---- phase A: as2 = a_s@Wsp ; av2_i = a_v_i@Wvp (lane = out channel) ----
    {
        float as2[8], ava[8], avb[8], avc[8];
#pragma unroll
        for (int nn = 0; nn < 8; nn++) { as2[nn]=0.f; ava[nn]=0.f; avb[nn]=0.f; avc[nn]=0.f; }
        for (int c = 0; c < 64; c++) {
            float wsp = Wsp[c * 64 + lane];
            float wvp = Wvp[c * 64 + lane];
#pragma unroll
            for (int nn = 0; nn < 8; nn++) {
                as2[nn] += X[nn * 256 + c] * wsp;
                ava[nn] += X[nn * 256 + 64 + c] * wvp;
                avb[nn] += X[nn * 256 + 128 + c] * wvp;
                avc[nn] += X[nn * 256 + 192 + c] * wvp;
            }
        }
#pragma unroll
        for (int nn = 0; nn < 8; nn++) {   // in-place (all reads done)
            X[nn * 256 + lane] = as2[nn];
            X[nn * 256 + 64 + lane] = ava[nn];
            X[nn * 256 + 128 + lane] = avb[nn];
            X[nn * 256 + 192 + lane] = avc[nn];
        }
    }

    // ---- phase B: ps, pv ----
    {
        float ps[8], pv0[8], pv1[8], pv2[8];
#pragma unroll
        for (int nn = 0; nn < 8; nn++) { ps[nn]=0.f; pv0[nn]=0.f; pv1[nn]=0.f; pv2[nn]=0.f; }
        for (int c = 0; c < 64; c++) {
            float p1 = Ps1[c * 64 + lane], p2 = Ps2[c * 64 + lane],
                  p3 = Ps3[c * 64 + lane], pv = Pvv[c * 64 + lane];
            float q1 = Pv1[c * 64 + lane], q2 = Pv2[c * 64 + lane],
                  q3 = Pv3[c * 64 + lane];
#pragma unroll
            for (int nn = 0; nn < 8; nn++) {
                float a  = X[nn * 256 + c];
                float b0 = X[nn * 256 + 64 + c];
                float b1 = X[nn * 256 + 128 + c];
                float b2 = X[nn * 256 + 192 + c];
                float a2 = a * a, a3 = a2 * a;
                float vv = b0 * b0 + b1 * b1 + b2 * b2;
                ps[nn] += a * p1 + a2 * p2 + a3 * p3 + vv * pv;
                float qq = q1 + a * q2 + a2 * q3;
                pv0[nn] += b0 * qq; pv1[nn] += b1 * qq; pv2[nn] += b2 * qq;
            }
        }
#pragma unroll
        for (int nn = 0; nn < 8; nn++) {
            Y[nn * 256 + lane] = ps[nn];
            Y[nn * 256 + 64 + lane] = pv0[nn];
            Y[nn * 256 + 128 + lane] = pv1[nn];
            Y[nn * 256 + 192 + lane] = pv2[nn];
            int n = nb + nn;
            if (n < Nn) {   // node_feats_out = [ps | pv (k*3+i)]
                float* nf = out + NF_OFF + (size_t)n * 256;
                nf[lane] = ps[nn];
                nf[64 + lane * 3 + 0] = pv0[nn];
                nf[64 + lane * 3 + 1] = pv1[nn];
                nf[64 + lane * 3 + 2] = pv2[nn];
            }
        }
    }

    // ---- phase C: hr = silu(ps @ Rw1) -> X s-section (dead) ----
    {
        float hr[8];
#pragma unroll
        for (int nn = 0; nn < 8; nn++) hr[nn] = 0.f;
        for (int c = 0; c < 64; c++) {
            float r1 = Rw1[c * 64 + lane];
#pragma unroll
            for (int nn = 0; nn < 8; nn++) hr[nn] += Y[nn * 256 + c] * r1;
        }
#pragma unroll
        for (int nn = 0; nn < 8; nn++) X[nn * 256 + lane] = silu(hr[nn]);
    }

    // ---- gate = silu(hr @ Rgate) : per-node wave reduction ----
    float gate[8];
    {
        float rg = Rgate[lane];
#pragma unroll
        for (int nn = 0; nn < 8; nn++) {
            float p = X[nn * 256 + lane] * rg;
            p += __shfl_xor(p, 1);  p += __shfl_xor(p, 2);
            p += __shfl_xor(p, 4);  p += __shfl_xor(p, 8);
            p += __shfl_xor(p, 16); p += __shfl_xor(p, 32);
            gate[nn] = silu(p);
        }
    }

    // ---- out_s = hr @ Rw2 ----
    {
        float os[8];
#pragma unroll
        for (int nn = 0; nn < 8; nn++) os[nn] = 0.f;
        for (int c = 0; c < 64; c++) {
            float r2 = Rw2[c * 64 + lane];
#pragma unroll
            for (int nn = 0; nn < 8; nn++) os[nn] += X[nn * 256 + c] * r2;
        }
#pragma unroll
        for (int nn = 0; nn < 8; nn++) {
            int n = nb + nn;
            if (n < Nn) out[(size_t)n * 64 + lane] = os[nn];
        }
    }

    // ---- vec = (sum_k pv_i[k]*Rvmix[k]) * gate ----
    {
        float vm = Rvmix[lane];
#pragma unroll
        for (int nn = 0; nn < 8; nn++) {
            int n = nb + nn;
#pragma unroll
            for (int j = 0; j < 3; j++) {
                float p = Y[nn * 256 + 64 + j * 64 + lane] * vm;
                p += __shfl_xor(p, 1);  p += __shfl_xor(p, 2);
                p += __shfl_xor(p, 4);  p += __shfl_xor(p, 8);
                p += __shfl_xor(p, 16); p += __shfl_xor(p, 32);
                if (lane == j && n < Nn)
                    out[VEC_OFF + (size_t)n * 3 + j] = p * gate[nn];
            }
        }
    }
}

// ---------------- host ----------------
extern "C" void kernel_launch(void* const* d_in, const int* in_sizes, int n_in,
                              void* d_out, int out_size, void* d_ws, size_t ws_size,
                              hipStream_t stream) {
    (void)in_sizes; (void)n_in; (void)out_size; (void)ws_size;
    const float* vectors    = (const float*)d_in[0];
    const float* node_feats = (const float*)d_in[2];
    const float* edge_feats = (const float*)d_in[3];
    const int*   edge_index = (const int*)d_in[4];
    const float* W_s_up   = (const float*)d_in[5];
    const float* W_v_up   = (const float*)d_in[6];
    const float* mlp_w1   = (const float*)d_in[7];
    const float* mlp_w2   = (const float*)d_in[8];
    const float* W_s_post = (const float*)d_in[9];
    const float* W_v_post = (const float*)d_in[10];
    const float* P_s1 = (const float*)d_in[11];
    const float* P_s2 = (const float*)d_in[12];
    const float* P_s3 = (const float*)d_in[13];
    const float* P_vv = (const float*)d_in[14];
    const float* P_v1 = (const float*)d_in[15];
    const float* P_v2 = (const float*)d_in[16];
    const float* P_v3 = (const float*)d_in[17];
    const float* R_w1 = (const float*)d_in[18];
    const float* R_w2 = (const float*)d_in[19];
    const float* R_gate = (const float*)d_in[20];
    const float* R_vmix = (const float*)d_in[21];

    char* ws = (char*)d_ws;
    float* a_s = (float*)(ws + AS_OFF);
    float* a_v = (float*)(ws + AV_OFF);
    float* outp = (float*)d_out;
    // scratch for per-node up-projection: node_feats_out region of the
    // output buffer (N*256 f32 = 51.2 MB). Written by k_up, read by
    // k_edge, overwritten by k_post at the end.
    float* up = outp + NF_OFF;

    // zero segment-sum accumulators (51.2 MB)
    hipMemsetAsync(ws, 0, 51200000, stream);

    k_up<<<(Nn + 31) / 32, 256, 0, stream>>>(node_feats, W_s_up, W_v_up, up);

    k_edge<<<Ee / 32, 256, 0, stream>>>(vectors, edge_feats,
                                        edge_index, edge_index + Ee,
                                        up, mlp_w1, mlp_w2, a_s, a_v);

    k_post<<<(Nn + 31) / 32, 256, 0, stream>>>(a_s, a_v,
                                               W_s_post, W_v_post,
                                               P_s1, P_s2, P_s3, P_vv,
                                               P_v1, P_v2, P_v3,
                                               R_w1, R_w2, R_gate, R_vmix,
                                               outp);
}